// Round 6
// baseline (273.079 us; speedup 1.0000x reference)
//
#include <hip/hip_runtime.h>

// ---------------------------------------------------------------------------
// On-device Clebsch-Gordan tables (exact port of _su2_cg/_q/_real_cg/_build_K,
// fp64).  Factorials from constant LUT; su2_cg precomputed into a dense table.
// ---------------------------------------------------------------------------
__device__ __constant__ double FACT[12] = {
    1.0, 1.0, 2.0, 6.0, 24.0, 120.0, 720.0, 5040.0,
    40320.0, 362880.0, 3628800.0, 39916800.0
};

struct cplx { double re, im; };
__device__ __forceinline__ cplx cmul(cplx a, cplx b) {
    return { a.re * b.re - a.im * b.im, a.re * b.im + a.im * b.re };
}

__device__ double su2_cg_full(int j1, int j2, int j3, int m1, int m2, int m3) {
    if (j3 < abs(j1 - j2) || j3 > j1 + j2) return 0.0;
    if (abs(m1) > j1 || abs(m2) > j2 || abs(m3) > j3) return 0.0;
    if (m3 != m1 + m2) return 0.0;
    int vmin = max(max(-j1 + j2 + m3, -j1 + m1), 0);
    int vmax = min(min(j2 + j3 + m1, j3 - j1 + j2), j3 + m3);
    if (vmax < vmin) return 0.0;
    double C = sqrt((2.0 * j3 + 1.0) * FACT[j3 + j1 - j2] * FACT[j3 - j1 + j2] *
                    FACT[j1 + j2 - j3] / FACT[j1 + j2 + j3 + 1] *
                    FACT[j3 + m3] * FACT[j3 - m3] /
                    (FACT[j1 - m1] * FACT[j1 + m1] * FACT[j2 - m2] * FACT[j2 + m2]));
    double S = 0.0;
    for (int v = vmin; v <= vmax; ++v) {
        double sgn = ((v + j2 + m2) & 1) ? -1.0 : 1.0;
        S += sgn / FACT[v] * FACT[j2 + j3 + m1 - v] * FACT[j1 - m1 + v] /
             FACT[j3 - j1 + j2 - v] / FACT[j3 + m3 - v] / FACT[v + j1 - j2 - m3];
    }
    return C * S;
}

__device__ __forceinline__ int su2_idx(int l1, int l2, int l3, int m1, int m2, int m3) {
    return ((((l1 * 3 + l2) * 6 + l3) * 7 + (m1 + 3)) * 5 + (m2 + 2)) * 11 + (m3 + 5);
}
#define SU2_TAB_SIZE 27720  // 4*3*6*7*5*11

__device__ int q_col(int l, int c0, int* rows, cplx* vals) {
    const double s = 0.7071067811865476;
    cplx ph;  // (-i)^l
    switch (l & 3) {
        case 0: ph = {1.0, 0.0}; break;
        case 1: ph = {0.0, -1.0}; break;
        case 2: ph = {-1.0, 0.0}; break;
        default: ph = {0.0, 1.0}; break;
    }
    int mu = c0 - l;
    if (mu == 0) { rows[0] = l; vals[0] = ph; return 1; }
    if (mu > 0) {
        rows[0] = l - mu; vals[0] = cmul(ph, {s, 0.0});
        double sg = (mu & 1) ? -1.0 : 1.0;
        rows[1] = l + mu; vals[1] = cmul(ph, {sg * s, 0.0});
        return 2;
    }
    int am = -mu;
    rows[0] = l - am; vals[0] = cmul(ph, {0.0, -s});
    double sg = (am & 1) ? -1.0 : 1.0;
    rows[1] = l + am; vals[1] = cmul(ph, {0.0, sg * s});
    return 2;
}

__device__ float real_cg_elem_tab(const double* __restrict__ su2tab,
                                  int l1, int l2, int l3, int a, int b, int c) {
    int r1[2], r2[2], r3[2];
    cplx v1[2], v2[2], v3[2];
    int n1 = q_col(l1, a, r1, v1);
    int n2 = q_col(l2, b, r2, v2);
    int n3 = q_col(l3, c, r3, v3);
    double re = 0.0;
    for (int x = 0; x < n1; ++x)
        for (int y = 0; y < n2; ++y)
            for (int z = 0; z < n3; ++z) {
                cplx qq = cmul(v1[x], v2[y]);
                cplx q3c = { v3[z].re, -v3[z].im };
                qq = cmul(qq, q3c);
                double cg = su2tab[su2_idx(l1, l2, l3, r1[x] - l1, r2[y] - l2, r3[z] - l3)];
                re += qq.re * cg;
            }
    return (float)re;
}

__device__ int flsqrt(int x) {
    int l = 0;
    while ((l + 1) * (l + 1) <= x) ++l;
    return l;
}

__device__ __forceinline__ void sh_from_delta(float dx, float dy, float dz, float* Y) {
    float inv = 1.f / (sqrtf(dx * dx + dy * dy + dz * dz) + 1e-12f);
    float x = dx * inv, y = dy * inv, z = dz * inv;
    const float c1 = 0.4886025119029199f;
    const float c2a = 1.0925484305920792f;
    Y[0] = 0.28209479177387814f;
    Y[1] = c1 * y; Y[2] = c1 * z; Y[3] = c1 * x;
    Y[4] = c2a * x * y;
    Y[5] = c2a * y * z;
    Y[6] = 0.31539156525252005f * (3.f * z * z - 1.f);
    Y[7] = c2a * x * z;
    Y[8] = 0.5462742152960396f * (x * x - y * y);
}

// table-assembly helper shared by phase2bin_k (new) and phase2_k (old)
__device__ void tbl2_work(const double* __restrict__ su2tab, int t,
                          float* __restrict__ A1, float* __restrict__ K2) {
    const int NK2 = 16 * 9 * 36;
    if (t < NK2) {
        int k = t % 36;
        int j = (t / 36) % 9;
        int i = t / (36 * 9);
        int l1 = flsqrt(i), l2 = flsqrt(j), l3 = flsqrt(k);
        float v = 0.f;
        if (l3 >= abs(l1 - l2) && l3 <= l1 + l2)
            v = real_cg_elem_tab(su2tab, l1, l2, l3, i - l1 * l1, j - l2 * l2, k - l3 * l3);
        K2[t] = v;
    } else if (t < NK2 + 144) {
        int u = t - NK2;
        int j = u / 16, k = u % 16;
        int l2 = flsqrt(j), l3 = flsqrt(k);
        float v = 0.f;
        for (int i = 0; i < 4; ++i) {
            int l1 = flsqrt(i);
            if (l3 >= abs(l1 - l2) && l3 <= l1 + l2 && l3 <= 3)
                v += real_cg_elem_tab(su2tab, l1, l2, l3, i - l1 * l1, j - l2 * l2, k - l3 * l3);
        }
        A1[u] = v;
    }
}

// ---------------------------------------------------------------------------
// Phase 1: [su2 table] || [zero a caller-chosen region]
// ---------------------------------------------------------------------------
#define SU2_BLOCKS 109  // ceil(27720/256)
__global__ __launch_bounds__(256) void phase1_k(double* __restrict__ su2tab,
                                                float* __restrict__ zero_base,
                                                long zeroN) {
    if (blockIdx.x < SU2_BLOCKS) {
        int t = blockIdx.x * 256 + threadIdx.x;
        if (t < SU2_TAB_SIZE) {
            int r = t;
            int im3 = r % 11; r /= 11;
            int im2 = r % 5;  r /= 5;
            int im1 = r % 7;  r /= 7;
            int l3  = r % 6;  r /= 6;
            int l2  = r % 3;  r /= 3;
            int l1  = r;
            su2tab[t] = su2_cg_full(l1, l2, l3, im1 - 3, im2 - 2, im3 - 5);
        }
    } else {
        long zb = blockIdx.x - SU2_BLOCKS;
        long nzb = gridDim.x - SU2_BLOCKS;
        long n4 = zeroN >> 2;
        float4* p = (float4*)zero_base;
        for (long i = zb * 256 + threadIdx.x; i < n4; i += nzb * 256)
            p[i] = float4{0.f, 0.f, 0.f, 0.f};
        for (long i = (n4 << 2) + zb * 256 + threadIdx.x; i < zeroN; i += nzb * 256)
            zero_base[i] = 0.f;
    }
}

#define TBL2_BLOCKS 21  // ceil(5328/256)
#define OLCAP 16384
#define NS 8      // stripes per graph: stripe = blockIdx&7 -> fixed XCD under
                  // round-robin dispatch, so each glist segment + its counter
                  // are written by one XCD (no cross-XCD line/atomic ping-pong)
#define CHB 512   // edges per bin block -> 1600 blocks (round-1 starved at 400)
#define BCAP 44   // LDS bin capacity; mean 8/bin (Poisson tail ~1e-22)

// ---------------------------------------------------------------------------
// Phase 2bin (NEW): [K2/A1] || LDS-aggregated binning by receiver graph.
// Evidence r0/r3/r5: the direct scatter's cost is 819K scattered global
// atomicAdds (~45-65us), not traffic.  Here each block LDS-bins its 512 edges
// (LDS atomics, ~free), then reserves glist space with ONE global atomic per
// (graph-bin, block) -> ~102K global atomics total (8x fewer), and flushes
// coalesced.  Spill (essentially impossible: caps are >=20 sigma): Y folded
// into SYs stripe-0 by global atomics + olist replay in final3.
// ---------------------------------------------------------------------------
__global__ __launch_bounds__(256) void phase2bin_k(const double* __restrict__ su2tab,
                                                   float* __restrict__ A1,
                                                   float* __restrict__ K2,
                                                   const int* __restrict__ rcv,
                                                   const int* __restrict__ snd,
                                                   const float* __restrict__ pos,
                                                   int* __restrict__ gcount,
                                                   int* __restrict__ glist,
                                                   int* __restrict__ olcnt,
                                                   uint2* __restrict__ olist,
                                                   float* __restrict__ SYs0,
                                                   int E, int npg, int scap) {
    if (blockIdx.x < TBL2_BLOCKS) {
        tbl2_work(su2tab, blockIdx.x * 256 + threadIdx.x, A1, K2);
        return;
    }
    __shared__ int cnt[64];
    __shared__ int lst[64 * BCAP];
    for (int t = threadIdx.x; t < 64; t += 256) cnt[t] = 0;
    __syncthreads();
    int st = blockIdx.x & (NS - 1);
    int e0 = (blockIdx.x - TBL2_BLOCKS) * CHB;
    for (int i = threadIdx.x; i < CHB; i += 256) {
        int e = e0 + i;
        if (e >= E) continue;
        int r = rcv[e], s = snd[e];
        int g = r / npg;
        int rl = r - g * npg;
        int packed = (rl << 16) | s;
        int sl = atomicAdd(&cnt[g], 1);
        if (sl < BCAP) {
            lst[g * BCAP + sl] = packed;
        } else {
            float Y[9];
            sh_from_delta(pos[3 * r] - pos[3 * s], pos[3 * r + 1] - pos[3 * s + 1],
                          pos[3 * r + 2] - pos[3 * s + 2], Y);
#pragma unroll
            for (int j = 0; j < 9; ++j) atomicAdd(&SYs0[(size_t)r * 9 + j], Y[j]);
            int ob = atomicAdd(olcnt, 1);
            if (ob < OLCAP) olist[ob] = uint2{(unsigned)r, (unsigned)s};
        }
    }
    __syncthreads();
    int wid = threadIdx.x >> 6, lane = threadIdx.x & 63;
    for (int g = wid * 16; g < wid * 16 + 16; ++g) {
        int c = min(cnt[g], BCAP);
        if (c == 0) continue;
        int base = 0;
        if (lane == 0) base = atomicAdd(&gcount[g * NS + st], c);
        base = __shfl(base, 0, 64);
        for (int k = lane; k < c; k += 64) {
            int dst = base + k;
            int p = lst[g * BCAP + k];
            if (dst < scap) {
                glist[(size_t)(g * NS + st) * scap + dst] = p;
            } else {
                int rl = ((unsigned)p) >> 16;
                int s = p & 0xFFFF;
                int r = g * npg + rl;
                float Y[9];
                sh_from_delta(pos[3 * r] - pos[3 * s], pos[3 * r + 1] - pos[3 * s + 1],
                              pos[3 * r + 2] - pos[3 * s + 2], Y);
#pragma unroll
                for (int j = 0; j < 9; ++j) atomicAdd(&SYs0[(size_t)r * 9 + j], Y[j]);
                int ob = atomicAdd(olcnt, 1);
                if (ob < OLCAP) olist[ob] = uint2{(unsigned)r, (unsigned)s};
            }
        }
    }
}

// ---------------------------------------------------------------------------
// Phase 2sy (NEW): per-(graph,stripe) SY accumulation in LDS (zero global
// atomics).  512 blocks (2/CU at 36.9KB LDS) vs round-4's starved 64.
// Stripe-major SYs[st][N][9]; stripe-0 block ACCUMULATES (+=) to preserve
// spill atomics from phase2bin.  Merged into SY[n*16+..] by merge_k.
// ---------------------------------------------------------------------------
__global__ __launch_bounds__(256) void phase2sy_k(const int* __restrict__ gcount,
                                                  const int* __restrict__ glist,
                                                  const float* __restrict__ pos,
                                                  float* __restrict__ SYs,
                                                  int N, int npg, int scap) {
    __shared__ float sy[1024 * 9];
    int bid = blockIdx.x;
    int g = bid >> 3, st = bid & 7;
    int n9 = npg * 9;
    for (int i = threadIdx.x; i < n9; i += 256) sy[i] = 0.f;
    __syncthreads();
    int c = min(gcount[g * NS + st], scap);
    const int* seg = glist + (size_t)(g * NS + st) * scap;
    for (int i = threadIdx.x; i < c; i += 256) {
        int p = seg[i];
        int rl = ((unsigned)p) >> 16;
        int s = p & 0xFFFF;
        int r = g * npg + rl;
        float Y[9];
        sh_from_delta(pos[3 * r] - pos[3 * s], pos[3 * r + 1] - pos[3 * s + 1],
                      pos[3 * r + 2] - pos[3 * s + 2], Y);
#pragma unroll
        for (int j = 0; j < 9; ++j) atomicAdd(&sy[rl * 9 + j], Y[j]);
    }
    __syncthreads();
    float* base = SYs + (size_t)st * N * 9 + (size_t)g * npg * 9;
    if (st == 0) {
        for (int i = threadIdx.x; i < n9; i += 256) base[i] += sy[i];
    } else {
        for (int i = threadIdx.x; i < n9; i += 256) base[i] = sy[i];
    }
}

// ---------------------------------------------------------------------------
// merge (NEW): [T2/Cc tables] || SY[n*16+j] = Sum_st SYs[st][n][9+j].
// Streaming: 8*1.8MB reads + 1.8MB writes.
// ---------------------------------------------------------------------------
#define TBLM_BLOCKS 6  // ceil(1450/256)
__global__ __launch_bounds__(256) void merge_k(const float* __restrict__ SYs,
                                               float* __restrict__ SY,
                                               const float* __restrict__ K2,
                                               const float* __restrict__ wg,
                                               const float* __restrict__ b2,
                                               const float* __restrict__ bg,
                                               float* __restrict__ T2,
                                               float* __restrict__ Cc,
                                               int N, int npg) {
    if (blockIdx.x < TBLM_BLOCKS) {
        int t = blockIdx.x * 256 + threadIdx.x;
        if (t < 1440) {
            int c = t % 10;
            int ij = t / 10;
            float acc = 0.f;
            for (int k = 0; k < 36; ++k)
                acc += K2[ij * 36 + k] * (wg[k * 10 + c] + wg[(36 + k) * 10 + c]);
            T2[t] = acc;
        } else if (t < 1450) {
            int c = t - 1440;
            float sw = 0.f;
            for (int k = 0; k < 36; ++k) sw += wg[k * 10 + c] + wg[(36 + k) * 10 + c];
            Cc[c] = (float)npg * b2[0] * sw + bg[c];
        }
        return;
    }
    int n = (blockIdx.x - TBLM_BLOCKS) * 256 + threadIdx.x;
    if (n >= N) return;
    float v[9];
#pragma unroll
    for (int j = 0; j < 9; ++j) v[j] = SYs[(size_t)n * 9 + j];
    for (int st = 1; st < NS; ++st) {
        const float* b = SYs + (size_t)st * N * 9 + (size_t)n * 9;
#pragma unroll
        for (int j = 0; j < 9; ++j) v[j] += b[j];
    }
#pragma unroll
    for (int j = 0; j < 9; ++j) SY[n * 16 + j] = v[j];
}

// ---------------------------------------------------------------------------
// Phase 2 (OLD fallback): [K2/A1] || [per-node scatter with global atomics,
// column-major bucket, overflow folded into SY only]
// ---------------------------------------------------------------------------
__global__ __launch_bounds__(256) void phase2_k(const double* __restrict__ su2tab,
                                                float* __restrict__ A1,
                                                float* __restrict__ K2,
                                                const int* __restrict__ rcv,
                                                const int* __restrict__ snd,
                                                const float* __restrict__ pos,
                                                int* __restrict__ count,
                                                int* __restrict__ bucket,
                                                float* __restrict__ SY,
                                                int E, int N, int slots) {
    if (blockIdx.x < TBL2_BLOCKS) {
        tbl2_work(su2tab, blockIdx.x * 256 + threadIdx.x, A1, K2);
        return;
    }
    int e = (blockIdx.x - TBL2_BLOCKS) * 256 + threadIdx.x;
    if (e >= E) return;
    int r = rcv[e];
    int s = snd[e];
    int slot = atomicAdd(&count[r], 1);
    if (slot < slots) {
        bucket[(size_t)slot * N + r] = s;
    } else {
        float Y[9];
        sh_from_delta(pos[3 * r] - pos[3 * s], pos[3 * r + 1] - pos[3 * s + 1],
                      pos[3 * r + 2] - pos[3 * s + 2], Y);
#pragma unroll
        for (int j = 0; j < 9; ++j) atomicAdd(&SY[r * 16 + j], Y[j]);
    }
}

// ---------------------------------------------------------------------------
// Phase 3 (OLD path only): [T2/Cc] || [per-node gather -> SY, 2 threads/node]
// ---------------------------------------------------------------------------
#define TBL3_BLOCKS 6  // ceil(1450/256)
__global__ __launch_bounds__(256) void phase3_k(const float* __restrict__ K2,
                                                const float* __restrict__ wg,
                                                const float* __restrict__ b2,
                                                const float* __restrict__ bg,
                                                int npg,
                                                float* __restrict__ T2,
                                                float* __restrict__ Cc,
                                                const float* __restrict__ pos,
                                                const int* __restrict__ count,
                                                const int* __restrict__ bucket,
                                                float* __restrict__ SY,
                                                int N, int slots) {
    if (blockIdx.x < TBL3_BLOCKS) {
        int t = blockIdx.x * 256 + threadIdx.x;
        if (t < 1440) {
            int c = t % 10;
            int ij = t / 10;
            float acc = 0.f;
            for (int k = 0; k < 36; ++k)
                acc += K2[ij * 36 + k] * (wg[k * 10 + c] + wg[(36 + k) * 10 + c]);
            T2[t] = acc;
        } else if (t < 1450) {
            int c = t - 1440;
            float sw = 0.f;
            for (int k = 0; k < 36; ++k) sw += wg[k * 10 + c] + wg[(36 + k) * 10 + c];
            Cc[c] = (float)npg * b2[0] * sw + bg[c];
        }
    } else {
        int i = (blockIdx.x - TBL3_BLOCKS) * 256 + threadIdx.x;
        int n = i >> 1, sub = i & 1;
        if (n >= N) return;
        float rx = pos[3 * n], ry = pos[3 * n + 1], rz = pos[3 * n + 2];
        int deg = min(count[n], slots);
        float acc[9];
#pragma unroll
        for (int j = 0; j < 9; ++j) acc[j] = 0.f;
        for (int d = sub; d < deg; d += 2) {
            int s = bucket[(size_t)d * N + n];
            float Y[9];
            sh_from_delta(rx - pos[3 * s], ry - pos[3 * s + 1], rz - pos[3 * s + 2], Y);
#pragma unroll
            for (int j = 0; j < 9; ++j) acc[j] += Y[j];
        }
#pragma unroll
        for (int j = 0; j < 9; ++j) acc[j] += __shfl_xor(acc[j], 1, 64);
        if (sub == 0) {
#pragma unroll
            for (int j = 0; j < 9; ++j) SY[n * 16 + j] += acc[j];  // merge overflow atomics
        }
    }
}

__device__ __forceinline__ void accum_edge_s(const float* __restrict__ pos,
                                             const float* __restrict__ SY,
                                             int s, float rx, float ry, float rz,
                                             float* acc) {
    float Y[9];
    sh_from_delta(rx - pos[3 * s], ry - pos[3 * s + 1], rz - pos[3 * s + 2], Y);
    const float4* sp = reinterpret_cast<const float4*>(&SY[s * 16]);
    float4 s0 = sp[0], s1 = sp[1];
    float sv[9] = { s0.x, s0.y, s0.z, s0.w, s1.x, s1.y, s1.z, s1.w, SY[s * 16 + 8] };
#pragma unroll
    for (int jp = 0; jp < 9; ++jp)
#pragma unroll
        for (int j = 0; j < 9; ++j)
            acc[jp * 9 + j] += sv[jp] * Y[j];
}

// ---------------------------------------------------------------------------
// Phase 4e (NEW): [G/H tables] || edge-major outer products per (g,stripe)
// segment (balanced by construction).  Register acc[90], block reduction to
// partial.  acc[81..89] stay zero; final3 adds the Sum_n SY[n] term (addsy=1).
// Verified structure from round 4 (absmax 0.0).
// ---------------------------------------------------------------------------
#define TBL4_BLOCKS 4  // ceil(900/256)
__global__ __launch_bounds__(256) void phase4e_k(const float* __restrict__ A1,
                                                 const float* __restrict__ T2,
                                                 float* __restrict__ G,
                                                 float* __restrict__ H,
                                                 const float* __restrict__ pos,
                                                 const int* __restrict__ gcount,
                                                 const int* __restrict__ glist,
                                                 const float* __restrict__ SY,
                                                 float* __restrict__ partial,
                                                 int npg, int scap) {
    if (blockIdx.x < TBL4_BLOCKS) {
        int t = blockIdx.x * 256 + threadIdx.x;
        if (t < 810) {
            int c = t % 10;
            int jj = t / 10;
            int j = jj % 9, jp = jj / 9;
            float acc = 0.f;
            for (int i = 0; i < 16; ++i)
                acc += A1[jp * 16 + i] * T2[(i * 9 + j) * 10 + c];
            G[jj * 10 + c] = acc;
        } else if (t < 900) {
            int u = t - 810;
            int c = u % 10, j = u / 10;
            float acc = 0.f;
            for (int i = 0; i < 16; ++i) acc += T2[(i * 9 + j) * 10 + c];
            H[j * 10 + c] = acc;
        }
        return;
    }
    int bid = blockIdx.x - TBL4_BLOCKS;
    int g = bid / NS, st = bid - g * NS;
    int c = min(gcount[g * NS + st], scap);
    const int* seg = glist + (size_t)(g * NS + st) * scap;
    float acc[90];
#pragma unroll
    for (int v = 0; v < 90; ++v) acc[v] = 0.f;
    for (int i = threadIdx.x; i < c; i += 256) {
        int p = seg[i];
        int rl = ((unsigned)p) >> 16;
        int s = p & 0xFFFF;
        int r = g * npg + rl;
        accum_edge_s(pos, SY, s, pos[3 * r], pos[3 * r + 1], pos[3 * r + 2], acc);
    }
    __shared__ float red[4][90];
#pragma unroll
    for (int v = 0; v < 90; ++v) {
        float x = acc[v];
#pragma unroll
        for (int m = 1; m < 64; m <<= 1) x += __shfl_xor(x, m, 64);
        acc[v] = x;
    }
    int lane = threadIdx.x & 63, wid = threadIdx.x >> 6;
    if (lane == 0) {
#pragma unroll
        for (int v = 0; v < 90; ++v) red[wid][v] = acc[v];
    }
    __syncthreads();
    for (int t = threadIdx.x; t < 90; t += 256) {
        float s = 0.f;
        for (int w = 0; w < 4; ++w) s += red[w][t];
        partial[(size_t)bid * 90 + t] = s;
    }
}

// ---------------------------------------------------------------------------
// Phase 4 (OLD fallback): [G/H] || [per-node outer product, node-major]
// ---------------------------------------------------------------------------
__global__ __launch_bounds__(256) void phase4_k(const float* __restrict__ A1,
                                                const float* __restrict__ T2,
                                                float* __restrict__ G,
                                                float* __restrict__ H,
                                                const float* __restrict__ pos,
                                                const int* __restrict__ snd,
                                                const int* __restrict__ rcv,
                                                const int* __restrict__ count,
                                                const int* __restrict__ bucket,
                                                const float* __restrict__ SY,
                                                float* __restrict__ partial,
                                                int N, int E, int slots, int npb, int K) {
    if (blockIdx.x < TBL4_BLOCKS) {
        int t = blockIdx.x * 256 + threadIdx.x;
        if (t < 810) {
            int c = t % 10;
            int jj = t / 10;
            int j = jj % 9, jp = jj / 9;
            float acc = 0.f;
            for (int i = 0; i < 16; ++i)
                acc += A1[jp * 16 + i] * T2[(i * 9 + j) * 10 + c];
            G[jj * 10 + c] = acc;
        } else if (t < 900) {
            int u = t - 810;
            int c = u % 10, j = u / 10;
            float acc = 0.f;
            for (int i = 0; i < 16; ++i) acc += T2[(i * 9 + j) * 10 + c];
            H[j * 10 + c] = acc;
        }
        return;
    }
    int bid = blockIdx.x - TBL4_BLOCKS;
    int node_local = (int)threadIdx.x % npb;
    int sub = (int)threadIdx.x / npb;
    int n = bid * npb + node_local;
    float acc[90];
#pragma unroll
    for (int v = 0; v < 90; ++v) acc[v] = 0.f;
    if (sub < K && n < N) {
        float rx = pos[3 * n], ry = pos[3 * n + 1], rz = pos[3 * n + 2];
        int deg = count[n];
        if (deg <= slots) {
            for (int d = sub; d < deg; d += K)
                accum_edge_s(pos, SY, bucket[(size_t)d * N + n], rx, ry, rz, acc);
        } else {
            for (int e = sub; e < E; e += K)
                if (rcv[e] == n) accum_edge_s(pos, SY, snd[e], rx, ry, rz, acc);
        }
        if (sub == 0) {
#pragma unroll
            for (int j = 0; j < 9; ++j) acc[81 + j] = SY[n * 16 + j];
        }
    }
    __shared__ float red[4][90];
#pragma unroll
    for (int v = 0; v < 90; ++v) {
        float x = acc[v];
#pragma unroll
        for (int m = 1; m < 64; m <<= 1) x += __shfl_xor(x, m, 64);
        acc[v] = x;
    }
    int lane = threadIdx.x & 63, wid = threadIdx.x >> 6;
    if (lane == 0) {
#pragma unroll
        for (int v = 0; v < 90; ++v) red[wid][v] = acc[v];
    }
    __syncthreads();
    int nw = blockDim.x >> 6;
    for (int t = threadIdx.x; t < 90; t += blockDim.x) {
        float s = 0.f;
        for (int w = 0; w < nw; ++w) s += red[w][t];
        partial[bid * 90 + t] = s;
    }
}

// ---------------------------------------------------------------------------
// Phase 5: one block per graph.  Partial-reduce + (addsy: Sum_n SY[n] term)
// + overflow-list outer products + final affine.
// ---------------------------------------------------------------------------
__global__ __launch_bounds__(128) void final3_k(const float* __restrict__ G,
                                                const float* __restrict__ H,
                                                const float* __restrict__ partial,
                                                const float* __restrict__ Cc,
                                                const float* __restrict__ w1,
                                                const float* __restrict__ b1,
                                                const float* __restrict__ w2,
                                                const float* __restrict__ pos,
                                                const float* __restrict__ SY,
                                                const int* __restrict__ olcnt,
                                                const uint2* __restrict__ olist,
                                                float* __restrict__ out,
                                                int bpg, int npg, int addsy) {
    __shared__ float Ms[90];
    __shared__ float Gs[810];
    __shared__ float Hs[90];
    int g = blockIdx.x;
    int tid = threadIdx.x;
    for (int t = tid; t < 810; t += 128) Gs[t] = G[t];
    for (int t = tid; t < 90; t += 128) Hs[t] = H[t];
    const float* pg = &partial[(size_t)g * bpg * 90];
    for (int v = tid; v < 90; v += 128) {
        float m = 0.f;
        for (int q = 0; q < bpg; ++q) m += pg[q * 90 + v];
        Ms[v] = m;
    }
    __syncthreads();
    if (addsy) {
        float ps[9];
#pragma unroll
        for (int j = 0; j < 9; ++j) ps[j] = 0.f;
        for (int rl = tid; rl < npg; rl += 128) {
            const float* q = &SY[(size_t)(g * npg + rl) * 16];
#pragma unroll
            for (int j = 0; j < 9; ++j) ps[j] += q[j];
        }
#pragma unroll
        for (int j = 0; j < 9; ++j) atomicAdd(&Ms[81 + j], ps[j]);
    }
    int oc = min(olcnt[0], OLCAP);
    for (int i = tid; i < oc; i += 128) {
        uint2 es = olist[i];
        int r = (int)es.x;
        if (r / npg != g) continue;
        int s = (int)es.y;
        float Y[9];
        sh_from_delta(pos[3 * r] - pos[3 * s], pos[3 * r + 1] - pos[3 * s + 1],
                      pos[3 * r + 2] - pos[3 * s + 2], Y);
#pragma unroll
        for (int jp = 0; jp < 9; ++jp) {
            float sv = SY[s * 16 + jp];
#pragma unroll
            for (int j = 0; j < 9; ++j) atomicAdd(&Ms[jp * 9 + j], sv * Y[j]);
        }
    }
    __syncthreads();
    if (tid < 10) {
        int c = tid;
        float z = 0.f;
#pragma unroll
        for (int idx = 0; idx < 81; ++idx) z += Gs[idx * 10 + c] * Ms[idx];
        float z2 = 0.f;
#pragma unroll
        for (int j = 0; j < 9; ++j) z2 += Hs[j * 10 + c] * Ms[81 + j];
        out[g * 10 + c] = w2[0] * (w1[0] * z + b1[0] * z2) + Cc[c];
    }
}

extern "C" void kernel_launch(void* const* d_in, const int* in_sizes, int n_in,
                              void* d_out, int out_size, void* d_ws, size_t ws_size,
                              hipStream_t stream) {
    const float* pos = (const float*)d_in[0];
    const float* w1  = (const float*)d_in[1];
    const float* b1  = (const float*)d_in[2];
    const float* w2  = (const float*)d_in[3];
    const float* b2  = (const float*)d_in[4];
    const float* wg  = (const float*)d_in[5];
    const float* bg  = (const float*)d_in[6];
    const int* snd   = (const int*)d_in[7];
    const int* rcv   = (const int*)d_in[8];

    int N = in_sizes[0] / 3;
    int E = in_sizes[7];
    int nG = out_size / 10;          // n_graphs
    int npg = N / nG;                // nodes per graph (800)

    float* ws = (float*)d_ws;
    float* A1  = ws + 0;       // 144
    float* K2  = ws + 144;     // 5184
    float* T2  = ws + 5328;    // 1440
    float* Cc  = ws + 6768;    // 16
    float* Gt  = ws + 6784;    // 816
    float* Ht  = ws + 7600;    // 96
    double* su2tab = (double*)(ws + 7696);        // 27720 doubles
    size_t c0 = 7696 + 2 * (size_t)SU2_TAB_SIZE;  // 63136
    size_t wsFloats = ws_size / 4;

    // ---- NEW layout ----
    // [gcount(512) | olcnt(16) | SYs(NS*N*9, stripe-major; stripe-0 is the
    //  spill target and is zeroed) | SY(16N) | glist(nG*NS*scap) |
    //  olist(2*OLCAP) | partial(nG*NS*90)]
    int meanps = E / (nG * NS) + 1;
    int scap = ((2 * meanps + 63) / 64) * 64;
    size_t gcount_off = c0;
    size_t olcnt_off  = c0 + 512;
    size_t sys_off    = c0 + 528;
    size_t sy_off     = sys_off + (size_t)NS * N * 9;
    size_t glist_off  = sy_off + 16 * (size_t)N;
    size_t olist_off  = glist_off + (size_t)nG * NS * (size_t)scap;
    size_t part_off   = olist_off + 2 * (size_t)OLCAP;
    size_t new_end    = part_off + (size_t)nG * NS * 90;
    bool newp = (N <= 65536) && (npg <= 1024) && (nG >= 1) && (nG <= 64) &&
                (npg * nG == N) && (scap >= meanps + 512) && (new_end <= wsFloats);

    if (newp) {
        int* gcount  = (int*)ws + gcount_off;
        int* olcnt   = (int*)ws + olcnt_off;
        float* SYs   = ws + sys_off;
        float* SY    = ws + sy_off;
        int* glist   = (int*)ws + glist_off;
        uint2* olist = (uint2*)(ws + olist_off);
        float* part  = ws + part_off;
        long zeroN = 528 + (long)N * 9;   // gcount + olcnt + SYs stripe-0
        phase1_k<<<SU2_BLOCKS + 128, 256, 0, stream>>>(su2tab, ws + c0, zeroN);
        int nBB = (E + CHB - 1) / CHB;
        phase2bin_k<<<TBL2_BLOCKS + nBB, 256, 0, stream>>>(
            su2tab, A1, K2, rcv, snd, pos, gcount, glist, olcnt, olist, SYs, E, npg, scap);
        phase2sy_k<<<nG * NS, 256, 0, stream>>>(gcount, glist, pos, SYs, N, npg, scap);
        merge_k<<<TBLM_BLOCKS + (N + 255) / 256, 256, 0, stream>>>(
            SYs, SY, K2, wg, b2, bg, T2, Cc, N, npg);
        phase4e_k<<<TBL4_BLOCKS + nG * NS, 256, 0, stream>>>(
            A1, T2, Gt, Ht, pos, gcount, glist, SY, part, npg, scap);
        final3_k<<<nG, 128, 0, stream>>>(Gt, Ht, part, Cc, w1, b1, w2, pos, SY,
                                         olcnt, olist, (float*)d_out, NS, npg, 1);
    } else {
        // ---- OLD fallback (round-5 wiring, column-major bucket) ----
        int npb = 1;
        for (int d = 1; d <= 64 && d <= npg; ++d) if (npg % d == 0) npb = d;
        int K = 256 / npb; if (K > 8) K = 8;
        int bpg = (npg > 0) ? npg / npb : 1;
        int NB2 = nG * bpg;
        int* count = (int*)ws + c0;
        float* SY  = ws + c0 + N;
        int* olcnt = (int*)ws + c0 + 17 * (size_t)N;
        size_t zeroN = 17 * (size_t)N + 16;
        size_t b0 = c0 + zeroN;
        float* part = ws + b0;
        size_t buck_off = b0 + (size_t)NB2 * 90;
        int* bucket = (int*)ws + buck_off;
        long avail = (long)wsFloats - (long)buck_off;
        int slots = 0;
        if (avail > 0) slots = (int)(avail / (long)N);
        if (slots > 48) slots = 48;
        phase1_k<<<SU2_BLOCKS + 128, 256, 0, stream>>>(su2tab, ws + c0, (long)zeroN);
        phase2_k<<<TBL2_BLOCKS + (E + 255) / 256, 256, 0, stream>>>(
            su2tab, A1, K2, rcv, snd, pos, count, bucket, SY, E, N, slots);
        phase3_k<<<TBL3_BLOCKS + (2 * N + 255) / 256, 256, 0, stream>>>(
            K2, wg, b2, bg, npg, T2, Cc, pos, count, bucket, SY, N, slots);
        phase4_k<<<TBL4_BLOCKS + NB2, 256, 0, stream>>>(
            A1, T2, Gt, Ht, pos, snd, rcv, count, bucket, SY, part, N, E, slots, npb, K);
        final3_k<<<nG, 128, 0, stream>>>(Gt, Ht, part, Cc, w1, b1, w2, pos, SY,
                                         olcnt, (uint2*)(ws + b0), (float*)d_out,
                                         bpg, npg, 0);
    }
}

// Round 7
// 105.081 us; speedup vs baseline: 2.5988x; 2.5988x over previous
//
#include <hip/hip_runtime.h>

// ---------------------------------------------------------------------------
// On-device Clebsch-Gordan tables (exact port of _su2_cg/_q/_real_cg/_build_K,
// fp64).  Factorials from constant LUT; su2_cg precomputed into a dense table.
// ---------------------------------------------------------------------------
__device__ __constant__ double FACT[12] = {
    1.0, 1.0, 2.0, 6.0, 24.0, 120.0, 720.0, 5040.0,
    40320.0, 362880.0, 3628800.0, 39916800.0
};

struct cplx { double re, im; };
__device__ __forceinline__ cplx cmul(cplx a, cplx b) {
    return { a.re * b.re - a.im * b.im, a.re * b.im + a.im * b.re };
}

__device__ double su2_cg_full(int j1, int j2, int j3, int m1, int m2, int m3) {
    if (j3 < abs(j1 - j2) || j3 > j1 + j2) return 0.0;
    if (abs(m1) > j1 || abs(m2) > j2 || abs(m3) > j3) return 0.0;
    if (m3 != m1 + m2) return 0.0;
    int vmin = max(max(-j1 + j2 + m3, -j1 + m1), 0);
    int vmax = min(min(j2 + j3 + m1, j3 - j1 + j2), j3 + m3);
    if (vmax < vmin) return 0.0;
    double C = sqrt((2.0 * j3 + 1.0) * FACT[j3 + j1 - j2] * FACT[j3 - j1 + j2] *
                    FACT[j1 + j2 - j3] / FACT[j1 + j2 + j3 + 1] *
                    FACT[j3 + m3] * FACT[j3 - m3] /
                    (FACT[j1 - m1] * FACT[j1 + m1] * FACT[j2 - m2] * FACT[j2 + m2]));
    double S = 0.0;
    for (int v = vmin; v <= vmax; ++v) {
        double sgn = ((v + j2 + m2) & 1) ? -1.0 : 1.0;
        S += sgn / FACT[v] * FACT[j2 + j3 + m1 - v] * FACT[j1 - m1 + v] /
             FACT[j3 - j1 + j2 - v] / FACT[j3 + m3 - v] / FACT[v + j1 - j2 - m3];
    }
    return C * S;
}

__device__ __forceinline__ int su2_idx(int l1, int l2, int l3, int m1, int m2, int m3) {
    return ((((l1 * 3 + l2) * 6 + l3) * 7 + (m1 + 3)) * 5 + (m2 + 2)) * 11 + (m3 + 5);
}
#define SU2_TAB_SIZE 27720  // 4*3*6*7*5*11

__device__ int q_col(int l, int c0, int* rows, cplx* vals) {
    const double s = 0.7071067811865476;
    cplx ph;  // (-i)^l
    switch (l & 3) {
        case 0: ph = {1.0, 0.0}; break;
        case 1: ph = {0.0, -1.0}; break;
        case 2: ph = {-1.0, 0.0}; break;
        default: ph = {0.0, 1.0}; break;
    }
    int mu = c0 - l;
    if (mu == 0) { rows[0] = l; vals[0] = ph; return 1; }
    if (mu > 0) {
        rows[0] = l - mu; vals[0] = cmul(ph, {s, 0.0});
        double sg = (mu & 1) ? -1.0 : 1.0;
        rows[1] = l + mu; vals[1] = cmul(ph, {sg * s, 0.0});
        return 2;
    }
    int am = -mu;
    rows[0] = l - am; vals[0] = cmul(ph, {0.0, -s});
    double sg = (am & 1) ? -1.0 : 1.0;
    rows[1] = l + am; vals[1] = cmul(ph, {0.0, sg * s});
    return 2;
}

__device__ float real_cg_elem_tab(const double* __restrict__ su2tab,
                                  int l1, int l2, int l3, int a, int b, int c) {
    int r1[2], r2[2], r3[2];
    cplx v1[2], v2[2], v3[2];
    int n1 = q_col(l1, a, r1, v1);
    int n2 = q_col(l2, b, r2, v2);
    int n3 = q_col(l3, c, r3, v3);
    double re = 0.0;
    for (int x = 0; x < n1; ++x)
        for (int y = 0; y < n2; ++y)
            for (int z = 0; z < n3; ++z) {
                cplx qq = cmul(v1[x], v2[y]);
                cplx q3c = { v3[z].re, -v3[z].im };
                qq = cmul(qq, q3c);
                double cg = su2tab[su2_idx(l1, l2, l3, r1[x] - l1, r2[y] - l2, r3[z] - l3)];
                re += qq.re * cg;
            }
    return (float)re;
}

__device__ int flsqrt(int x) {
    int l = 0;
    while ((l + 1) * (l + 1) <= x) ++l;
    return l;
}

__device__ __forceinline__ void sh_from_delta(float dx, float dy, float dz, float* Y) {
    float inv = 1.f / (sqrtf(dx * dx + dy * dy + dz * dz) + 1e-12f);
    float x = dx * inv, y = dy * inv, z = dz * inv;
    const float c1 = 0.4886025119029199f;
    const float c2a = 1.0925484305920792f;
    Y[0] = 0.28209479177387814f;
    Y[1] = c1 * y; Y[2] = c1 * z; Y[3] = c1 * x;
    Y[4] = c2a * x * y;
    Y[5] = c2a * y * z;
    Y[6] = 0.31539156525252005f * (3.f * z * z - 1.f);
    Y[7] = c2a * x * z;
    Y[8] = 0.5462742152960396f * (x * x - y * y);
}

// table-assembly helper shared by phase2d_k (new) and phase2_k (old)
__device__ void tbl2_work(const double* __restrict__ su2tab, int t,
                          float* __restrict__ A1, float* __restrict__ K2) {
    const int NK2 = 16 * 9 * 36;
    if (t < NK2) {
        int k = t % 36;
        int j = (t / 36) % 9;
        int i = t / (36 * 9);
        int l1 = flsqrt(i), l2 = flsqrt(j), l3 = flsqrt(k);
        float v = 0.f;
        if (l3 >= abs(l1 - l2) && l3 <= l1 + l2)
            v = real_cg_elem_tab(su2tab, l1, l2, l3, i - l1 * l1, j - l2 * l2, k - l3 * l3);
        K2[t] = v;
    } else if (t < NK2 + 144) {
        int u = t - NK2;
        int j = u / 16, k = u % 16;
        int l2 = flsqrt(j), l3 = flsqrt(k);
        float v = 0.f;
        for (int i = 0; i < 4; ++i) {
            int l1 = flsqrt(i);
            if (l3 >= abs(l1 - l2) && l3 <= l1 + l2 && l3 <= 3)
                v += real_cg_elem_tab(su2tab, l1, l2, l3, i - l1 * l1, j - l2 * l2, k - l3 * l3);
        }
        A1[u] = v;
    }
}

// ---------------------------------------------------------------------------
// Phase 1: [su2 table] || [zero count+SY+olcnt]
// ---------------------------------------------------------------------------
#define SU2_BLOCKS 109  // ceil(27720/256)
__global__ __launch_bounds__(256) void phase1_k(double* __restrict__ su2tab,
                                                float* __restrict__ zero_base,
                                                long zeroN) {
    if (blockIdx.x < SU2_BLOCKS) {
        int t = blockIdx.x * 256 + threadIdx.x;
        if (t < SU2_TAB_SIZE) {
            int r = t;
            int im3 = r % 11; r /= 11;
            int im2 = r % 5;  r /= 5;
            int im1 = r % 7;  r /= 7;
            int l3  = r % 6;  r /= 6;
            int l2  = r % 3;  r /= 3;
            int l1  = r;
            su2tab[t] = su2_cg_full(l1, l2, l3, im1 - 3, im2 - 2, im3 - 5);
        }
    } else {
        long zb = blockIdx.x - SU2_BLOCKS;
        long nzb = gridDim.x - SU2_BLOCKS;
        long n4 = zeroN >> 2;
        float4* p = (float4*)zero_base;
        for (long i = zb * 256 + threadIdx.x; i < n4; i += nzb * 256)
            p[i] = float4{0.f, 0.f, 0.f, 0.f};
        for (long i = (n4 << 2) + zb * 256 + threadIdx.x; i < zeroN; i += nzb * 256)
            zero_base[i] = 0.f;
    }
}

#define TBL2_BLOCKS 21  // ceil(5328/256)
#define OLCAP 16384
#define CH2D 2048       // edges per chunk; each chunk scanned by 8 blocks

// ---------------------------------------------------------------------------
// Phase 2d (NEW): XCD-partitioned direct scatter into ROW-MAJOR bucket, with
// PADDED degree counters: count[r*16] -- one counter per 64B cache line.
// Cross-round atomic model (r4: 12.8K atomics/line = 245us; r6: 3.2K/line =
// 165us; r5: 256/line = ~40us => ~50-160ns per same-line atomic, lines served
// in parallel): padding drops same-line chains 256 -> 16, predicted ~2x on
// this kernel.  The (rcv>>4)&7 == blockIdx&7 residue partition keeps each
// 16-node row group + its counter lines on ONE XCD (r5: 128->108us), and is
// exact, so correctness never depends on the dispatch heuristic.
// count[r*16] holds raw degree; overflow -> SY atomics + olist (BSLOT=40 =>
// expected overflow 0 at Poisson(16) in-degree).
// ---------------------------------------------------------------------------
__global__ __launch_bounds__(256) void phase2d_k(const double* __restrict__ su2tab,
                                                 float* __restrict__ A1,
                                                 float* __restrict__ K2,
                                                 const int* __restrict__ rcv,
                                                 const int* __restrict__ snd,
                                                 const float* __restrict__ pos,
                                                 int* __restrict__ count,
                                                 int* __restrict__ bucket,
                                                 int* __restrict__ olcnt,
                                                 uint2* __restrict__ olist,
                                                 float* __restrict__ SY,
                                                 int E, int bslot) {
    if (blockIdx.x < TBL2_BLOCKS) {
        tbl2_work(su2tab, blockIdx.x * 256 + threadIdx.x, A1, K2);
        return;
    }
    int w = blockIdx.x - TBL2_BLOCKS;
    int xcd = (int)(blockIdx.x & 7);   // match empirical round-robin dispatch
    int chunk = w >> 3;
    int base = chunk * CH2D;
    int end = min(base + CH2D, E);
    for (int e = base + (int)threadIdx.x; e < end; e += 256) {
        int r = rcv[e];
        if (((r >> 4) & 7) != xcd) continue;
        int s = snd[e];
        int slot = atomicAdd(&count[(size_t)r << 4], 1);
        if (slot < bslot) {
            bucket[(size_t)r * bslot + slot] = s;
        } else {
            float Y[9];
            sh_from_delta(pos[3 * r] - pos[3 * s], pos[3 * r + 1] - pos[3 * s + 1],
                          pos[3 * r + 2] - pos[3 * s + 2], Y);
#pragma unroll
            for (int j = 0; j < 9; ++j) atomicAdd(&SY[r * 16 + j], Y[j]);
            int ob = atomicAdd(olcnt, 1);
            if (ob < OLCAP) olist[ob] = uint2{(unsigned)r, (unsigned)s};
        }
    }
}

// ---------------------------------------------------------------------------
// Phase 2 (OLD fallback): [K2/A1] || [per-node scatter with global atomics,
// column-major bucket, unpadded count, overflow folded into SY only]
// ---------------------------------------------------------------------------
__global__ __launch_bounds__(256) void phase2_k(const double* __restrict__ su2tab,
                                                float* __restrict__ A1,
                                                float* __restrict__ K2,
                                                const int* __restrict__ rcv,
                                                const int* __restrict__ snd,
                                                const float* __restrict__ pos,
                                                int* __restrict__ count,
                                                int* __restrict__ bucket,
                                                float* __restrict__ SY,
                                                int E, int N, int slots) {
    if (blockIdx.x < TBL2_BLOCKS) {
        tbl2_work(su2tab, blockIdx.x * 256 + threadIdx.x, A1, K2);
        return;
    }
    int e = (blockIdx.x - TBL2_BLOCKS) * 256 + threadIdx.x;
    if (e >= E) return;
    int r = rcv[e];
    int s = snd[e];
    int slot = atomicAdd(&count[r], 1);
    if (slot < slots) {
        bucket[(size_t)slot * N + r] = s;
    } else {
        float Y[9];
        sh_from_delta(pos[3 * r] - pos[3 * s], pos[3 * r + 1] - pos[3 * s + 1],
                      pos[3 * r + 2] - pos[3 * s + 2], Y);
#pragma unroll
        for (int j = 0; j < 9; ++j) atomicAdd(&SY[r * 16 + j], Y[j]);
    }
}

// node -> (bucket base, stride) for unified old/new indexing
// NEW path: row-major per node (contiguous deg ints); OLD: strided by N.
__device__ __forceinline__ void node_addr(int n, int N, int npg, int bslot, int newp,
                                          long* base, int* stride) {
    if (newp) {
        *base = (long)n * bslot;
        *stride = 1;
    } else {
        *base = n;
        *stride = N;
    }
}

// ---------------------------------------------------------------------------
// Phase 3: [T2/Cc] || [per-node gather -> SY, 2 threads per node]
// cstride: count element stride (16 = padded new path, 1 = old path).
// ---------------------------------------------------------------------------
#define TBL3_BLOCKS 6  // ceil(1450/256)
__global__ __launch_bounds__(256) void phase3_k(const float* __restrict__ K2,
                                                const float* __restrict__ wg,
                                                const float* __restrict__ b2,
                                                const float* __restrict__ bg,
                                                int npg,
                                                float* __restrict__ T2,
                                                float* __restrict__ Cc,
                                                const float* __restrict__ pos,
                                                const int* __restrict__ count,
                                                const int* __restrict__ bucket,
                                                float* __restrict__ SY,
                                                int N, int slots, int newp, int cstride) {
    if (blockIdx.x < TBL3_BLOCKS) {
        int t = blockIdx.x * 256 + threadIdx.x;
        if (t < 1440) {
            int c = t % 10;
            int ij = t / 10;
            float acc = 0.f;
            for (int k = 0; k < 36; ++k)
                acc += K2[ij * 36 + k] * (wg[k * 10 + c] + wg[(36 + k) * 10 + c]);
            T2[t] = acc;
        } else if (t < 1450) {
            int c = t - 1440;
            float sw = 0.f;
            for (int k = 0; k < 36; ++k) sw += wg[k * 10 + c] + wg[(36 + k) * 10 + c];
            Cc[c] = (float)npg * b2[0] * sw + bg[c];
        }
    } else {
        int i = (blockIdx.x - TBL3_BLOCKS) * 256 + threadIdx.x;
        int n = i >> 1, sub = i & 1;
        if (n >= N) return;
        float rx = pos[3 * n], ry = pos[3 * n + 1], rz = pos[3 * n + 2];
        int deg = min(count[(size_t)n * cstride], slots);
        long nb; int st;
        node_addr(n, N, npg, slots, newp, &nb, &st);
        float acc[9];
#pragma unroll
        for (int j = 0; j < 9; ++j) acc[j] = 0.f;
        for (int d = sub; d < deg; d += 2) {
            int s = bucket[nb + (long)d * st];
            float Y[9];
            sh_from_delta(rx - pos[3 * s], ry - pos[3 * s + 1], rz - pos[3 * s + 2], Y);
#pragma unroll
            for (int j = 0; j < 9; ++j) acc[j] += Y[j];
        }
#pragma unroll
        for (int j = 0; j < 9; ++j) acc[j] += __shfl_xor(acc[j], 1, 64);
        if (sub == 0) {
#pragma unroll
            for (int j = 0; j < 9; ++j) SY[n * 16 + j] += acc[j];  // merge overflow atomics
        }
    }
}

__device__ __forceinline__ void accum_edge_s(const float* __restrict__ pos,
                                             const float* __restrict__ SY,
                                             int s, float rx, float ry, float rz,
                                             float* acc) {
    float Y[9];
    sh_from_delta(rx - pos[3 * s], ry - pos[3 * s + 1], rz - pos[3 * s + 2], Y);
    const float4* sp = reinterpret_cast<const float4*>(&SY[s * 16]);
    float4 s0 = sp[0], s1 = sp[1];
    float sv[9] = { s0.x, s0.y, s0.z, s0.w, s1.x, s1.y, s1.z, s1.w, SY[s * 16 + 8] };
#pragma unroll
    for (int jp = 0; jp < 9; ++jp)
#pragma unroll
        for (int j = 0; j < 9; ++j)
            acc[jp * 9 + j] += sv[jp] * Y[j];
}

// ---------------------------------------------------------------------------
// Phase 4: [G/H] || [per-node outer product, K subs/node, block reduction]
// NEW path: deg is clamped to BSLOT and the bucket is ALWAYS used -- overflow
// edges (count>BSLOT) are replayed exactly once from olist in final3_k, so the
// old full-E-scan branch (which would double-count them) must not run.
// ---------------------------------------------------------------------------
#define TBL4_BLOCKS 4  // ceil(900/256)
__global__ __launch_bounds__(256) void phase4_k(const float* __restrict__ A1,
                                                const float* __restrict__ T2,
                                                float* __restrict__ G,
                                                float* __restrict__ H,
                                                const float* __restrict__ pos,
                                                const int* __restrict__ snd,
                                                const int* __restrict__ rcv,
                                                const int* __restrict__ count,
                                                const int* __restrict__ bucket,
                                                const float* __restrict__ SY,
                                                float* __restrict__ partial,
                                                int N, int E, int slots, int npb, int K,
                                                int npg, int newp, int cstride) {
    if (blockIdx.x < TBL4_BLOCKS) {
        int t = blockIdx.x * 256 + threadIdx.x;
        if (t < 810) {
            int c = t % 10;
            int jj = t / 10;
            int j = jj % 9, jp = jj / 9;
            float acc = 0.f;
            for (int i = 0; i < 16; ++i)
                acc += A1[jp * 16 + i] * T2[(i * 9 + j) * 10 + c];
            G[jj * 10 + c] = acc;
        } else if (t < 900) {
            int u = t - 810;
            int c = u % 10, j = u / 10;
            float acc = 0.f;
            for (int i = 0; i < 16; ++i) acc += T2[(i * 9 + j) * 10 + c];
            H[j * 10 + c] = acc;
        }
        return;
    }
    int bid = blockIdx.x - TBL4_BLOCKS;
    int node_local = (int)threadIdx.x % npb;
    int sub = (int)threadIdx.x / npb;
    int n = bid * npb + node_local;
    float acc[90];
#pragma unroll
    for (int v = 0; v < 90; ++v) acc[v] = 0.f;
    if (sub < K && n < N) {
        float rx = pos[3 * n], ry = pos[3 * n + 1], rz = pos[3 * n + 2];
        int deg = count[(size_t)n * cstride];
        if (newp || deg <= slots) {
            if (deg > slots) deg = slots;  // overflow replayed via olist in final3
            long nb; int st;
            node_addr(n, N, npg, slots, newp, &nb, &st);
            for (int d = sub; d < deg; d += K)
                accum_edge_s(pos, SY, bucket[nb + (long)d * st], rx, ry, rz, acc);
        } else {
            // old-path pathological overflow: enumerate all edges
            for (int e = sub; e < E; e += K)
                if (rcv[e] == n) accum_edge_s(pos, SY, snd[e], rx, ry, rz, acc);
        }
        if (sub == 0) {
#pragma unroll
            for (int j = 0; j < 9; ++j) acc[81 + j] = SY[n * 16 + j];
        }
    }
    __shared__ float red[4][90];
#pragma unroll
    for (int v = 0; v < 90; ++v) {
        float x = acc[v];
#pragma unroll
        for (int m = 1; m < 64; m <<= 1) x += __shfl_xor(x, m, 64);
        acc[v] = x;
    }
    int lane = threadIdx.x & 63, wid = threadIdx.x >> 6;
    if (lane == 0) {
#pragma unroll
        for (int v = 0; v < 90; ++v) red[wid][v] = acc[v];
    }
    __syncthreads();
    int nw = blockDim.x >> 6;
    for (int t = threadIdx.x; t < 90; t += blockDim.x) {
        float s = 0.f;
        for (int w = 0; w < nw; ++w) s += red[w][t];
        partial[bid * 90 + t] = s;
    }
}

// ---------------------------------------------------------------------------
// Phase 5: one block per graph.  Partial-reduce + overflow-list outer products
// + final affine.
// ---------------------------------------------------------------------------
__global__ __launch_bounds__(128) void final3_k(const float* __restrict__ G,
                                                const float* __restrict__ H,
                                                const float* __restrict__ partial,
                                                const float* __restrict__ Cc,
                                                const float* __restrict__ w1,
                                                const float* __restrict__ b1,
                                                const float* __restrict__ w2,
                                                const float* __restrict__ pos,
                                                const float* __restrict__ SY,
                                                const int* __restrict__ olcnt,
                                                const uint2* __restrict__ olist,
                                                float* __restrict__ out,
                                                int bpg, int npg) {
    __shared__ float Ms[90];
    __shared__ float Gs[810];
    __shared__ float Hs[90];
    int g = blockIdx.x;
    int tid = threadIdx.x;
    for (int t = tid; t < 810; t += 128) Gs[t] = G[t];
    for (int t = tid; t < 90; t += 128) Hs[t] = H[t];
    const float* pg = &partial[(size_t)g * bpg * 90];
    for (int v = tid; v < 90; v += 128) {
        float m = 0.f;
        for (int q = 0; q < bpg; ++q) m += pg[q * 90 + v];
        Ms[v] = m;
    }
    __syncthreads();
    int oc = min(olcnt[0], OLCAP);
    for (int i = tid; i < oc; i += 128) {
        uint2 es = olist[i];
        int r = (int)es.x;
        if (r / npg != g) continue;
        int s = (int)es.y;
        float Y[9];
        sh_from_delta(pos[3 * r] - pos[3 * s], pos[3 * r + 1] - pos[3 * s + 1],
                      pos[3 * r + 2] - pos[3 * s + 2], Y);
#pragma unroll
        for (int jp = 0; jp < 9; ++jp) {
            float sv = SY[s * 16 + jp];
#pragma unroll
            for (int j = 0; j < 9; ++j) atomicAdd(&Ms[jp * 9 + j], sv * Y[j]);
        }
    }
    __syncthreads();
    if (tid < 10) {
        int c = tid;
        float z = 0.f;
#pragma unroll
        for (int idx = 0; idx < 81; ++idx) z += Gs[idx * 10 + c] * Ms[idx];
        float z2 = 0.f;
#pragma unroll
        for (int j = 0; j < 9; ++j) z2 += Hs[j * 10 + c] * Ms[81 + j];
        out[g * 10 + c] = w2[0] * (w1[0] * z + b1[0] * z2) + Cc[c];
    }
}

extern "C" void kernel_launch(void* const* d_in, const int* in_sizes, int n_in,
                              void* d_out, int out_size, void* d_ws, size_t ws_size,
                              hipStream_t stream) {
    const float* pos = (const float*)d_in[0];
    const float* w1  = (const float*)d_in[1];
    const float* b1  = (const float*)d_in[2];
    const float* w2  = (const float*)d_in[3];
    const float* b2  = (const float*)d_in[4];
    const float* wg  = (const float*)d_in[5];
    const float* bg  = (const float*)d_in[6];
    const int* snd   = (const int*)d_in[7];
    const int* rcv   = (const int*)d_in[8];

    int N = in_sizes[0] / 3;
    int E = in_sizes[7];
    int nG = out_size / 10;          // n_graphs
    int npg = N / nG;                // nodes per graph (800)
    int npb = 1;
    for (int d = 1; d <= 64 && d <= npg; ++d) if (npg % d == 0) npb = d;
    int K = 256 / npb; if (K > 8) K = 8;   // 800 -> npb=50, K=5
    int bpg = npg / npb;                   // blocks per graph (16)
    int NB2 = nG * bpg;                    // phase4 blocks (1024)

    float* ws = (float*)d_ws;
    float* A1  = ws + 0;       // 144
    float* K2  = ws + 144;     // 5184
    float* T2  = ws + 5328;    // 1440
    float* Cc  = ws + 6768;    // 16
    float* Gt  = ws + 6784;    // 816
    float* Ht  = ws + 7600;    // 96
    double* su2tab = (double*)(ws + 7696);        // 27720 doubles
    size_t c0 = 7696 + 2 * (size_t)SU2_TAB_SIZE;  // 63136
    size_t wsFloats = ws_size / 4;

    // ---- NEW layout (round-5 champion + padded counters) ----
    // [count(16N ints, one counter per 64B line) | SY(16N) | olcnt(16) |
    //  bucket(BSLOT*N, row-major per node) | olist(2*OLCAP) | partial(NB2*90)]
    const int BSLOT = 40;
    size_t sy_off    = c0 + 16 * (size_t)N;
    size_t olcnt_off = sy_off + 16 * (size_t)N;
    size_t zeroN     = 32 * (size_t)N + 16;
    size_t b0        = c0 + zeroN;
    size_t olist_off = b0 + (size_t)BSLOT * N;
    size_t part_off  = olist_off + 2 * (size_t)OLCAP;
    size_t new_end   = part_off + (size_t)NB2 * 90;
    bool newp = (npg * nG == N) && (nG > 0) && (new_end <= wsFloats);

    if (newp) {
        int* count   = (int*)ws + c0;
        float* SY    = ws + sy_off;
        int* olcnt   = (int*)ws + olcnt_off;
        int* bucket  = (int*)ws + b0;
        uint2* olist = (uint2*)(ws + olist_off);
        float* part  = ws + part_off;
        phase1_k<<<SU2_BLOCKS + 128, 256, 0, stream>>>(su2tab, ws + c0, (long)zeroN);
        int nCH = (E + CH2D - 1) / CH2D;
        phase2d_k<<<TBL2_BLOCKS + nCH * 8, 256, 0, stream>>>(
            su2tab, A1, K2, rcv, snd, pos, count, bucket, olcnt, olist, SY, E, BSLOT);
        phase3_k<<<TBL3_BLOCKS + (2 * N + 255) / 256, 256, 0, stream>>>(
            K2, wg, b2, bg, npg, T2, Cc, pos, count, bucket, SY, N, BSLOT, 1, 16);
        phase4_k<<<TBL4_BLOCKS + NB2, 256, 0, stream>>>(
            A1, T2, Gt, Ht, pos, snd, rcv, count, bucket, SY, part, N, E, BSLOT, npb, K,
            npg, 1, 16);
        final3_k<<<nG, 128, 0, stream>>>(Gt, Ht, part, Cc, w1, b1, w2, pos, SY,
                                         olcnt, olist, (float*)d_out, bpg, npg);
    } else {
        // ---- OLD fallback: unpadded count | SY | olcnt | part | bucket ----
        int* count = (int*)ws + c0;
        float* SY  = ws + c0 + N;
        int* olcnt = (int*)ws + c0 + 17 * (size_t)N;
        size_t zN  = 17 * (size_t)N + 16;
        size_t ob0 = c0 + zN;
        float* part = ws + ob0;
        size_t buck_off = ob0 + (size_t)NB2 * 90;
        int* bucket = (int*)ws + buck_off;
        long avail = (long)wsFloats - (long)buck_off;
        int slots = 0;
        if (avail > 0) slots = (int)(avail / (long)N);
        if (slots > 48) slots = 48;
        phase1_k<<<SU2_BLOCKS + 128, 256, 0, stream>>>(su2tab, ws + c0, (long)zN);
        phase2_k<<<TBL2_BLOCKS + (E + 255) / 256, 256, 0, stream>>>(
            su2tab, A1, K2, rcv, snd, pos, count, bucket, SY, E, N, slots);
        phase3_k<<<TBL3_BLOCKS + (2 * N + 255) / 256, 256, 0, stream>>>(
            K2, wg, b2, bg, npg, T2, Cc, pos, count, bucket, SY, N, slots, 0, 1);
        phase4_k<<<TBL4_BLOCKS + NB2, 256, 0, stream>>>(
            A1, T2, Gt, Ht, pos, snd, rcv, count, bucket, SY, part, N, E, slots, npb, K,
            npg, 0, 1);
        final3_k<<<nG, 128, 0, stream>>>(Gt, Ht, part, Cc, w1, b1, w2, pos, SY,
                                         olcnt, (uint2*)(ws + olist_off), (float*)d_out,
                                         bpg, npg);
    }
}